// Round 2
// baseline (1267.261 us; speedup 1.0000x reference)
//
#include <hip/hip_runtime.h>
#include <math.h>

#define TT 2048
#define HH 2048
#define ID 768
#define NE 32
#define KTOP 8
#define CAP 1024

typedef short bf16x8 __attribute__((ext_vector_type(8)));
typedef float f32x4 __attribute__((ext_vector_type(4)));

__device__ __forceinline__ unsigned short f2b(float f) {
  unsigned int u = __builtin_bit_cast(unsigned int, f);
  u += 0x7fff + ((u >> 16) & 1);   // round-to-nearest-even
  return (unsigned short)(u >> 16);
}

__device__ __forceinline__ void gload16(const unsigned short* g, void* l) {
  __builtin_amdgcn_global_load_lds(
      (const __attribute__((address_space(1))) unsigned int*)g,
      (__attribute__((address_space(3))) unsigned int*)l, 16, 0, 0);
}

// raw barrier + counted waitcnt (asm with memory clobber = compiler fence).
// __syncthreads() would emit s_waitcnt vmcnt(0) and kill the counted pipeline.
#define SBAR() asm volatile("s_barrier" ::: "memory")
#define VMCNT(n) asm volatile("s_waitcnt vmcnt(" #n ")" ::: "memory")

// ---------------- x -> bf16 pre-convert ----------------
__global__ __launch_bounds__(256) void cvt_x_kernel(const float* __restrict__ x,
                                                    unsigned short* __restrict__ xb) {
  const size_t i = ((size_t)blockIdx.x * 256 + threadIdx.x) * 8;
  const float4 a = *(const float4*)(x + i);
  const float4 b = *(const float4*)(x + i + 4);
  union { unsigned short us[8]; uint4 v; } p;
  p.us[0] = f2b(a.x); p.us[1] = f2b(a.y); p.us[2] = f2b(a.z); p.us[3] = f2b(a.w);
  p.us[4] = f2b(b.x); p.us[5] = f2b(b.y); p.us[6] = f2b(b.z); p.us[7] = f2b(b.w);
  *(uint4*)(xb + i) = p.v;
}

// ---------------- generic weight transpose+convert: in [E][R][C] f32 -> out [E][C][R] bf16 ----------------
__global__ __launch_bounds__(256) void cvt_w_kernel(const float* __restrict__ in,
                                                    unsigned short* __restrict__ out,
                                                    int R, int C) {
  __shared__ float tile[64][65];
  const int e = blockIdx.z;
  const int r0 = blockIdx.y * 64, c0 = blockIdx.x * 64;
  const int tid = threadIdx.x;
  const float* src = in + (size_t)e * R * C;
  const int rr = tid >> 4, c4 = tid & 15;
#pragma unroll
  for (int it = 0; it < 4; ++it) {
    const int r = it * 16 + rr;
    const float4 v = *(const float4*)(src + (size_t)(r0 + r) * C + c0 + c4 * 4);
    tile[r][c4 * 4 + 0] = v.x; tile[r][c4 * 4 + 1] = v.y;
    tile[r][c4 * 4 + 2] = v.z; tile[r][c4 * 4 + 3] = v.w;
  }
  __syncthreads();
  unsigned short* dst = out + (size_t)e * R * C;
#pragma unroll
  for (int it = 0; it < 2; ++it) {
    const int task = tid + it * 256;
    const int c = task >> 3, g = task & 7;
    union { unsigned short us[8]; uint4 v; } p;
#pragma unroll
    for (int j = 0; j < 8; ++j) p.us[j] = f2b(tile[g * 8 + j][c]);
    *(uint4*)(dst + (size_t)(c0 + c) * R + r0 + g * 8) = p.v;
  }
}

// ---------------- wgu transpose+convert WITH gate/up interleave ----------------
// source [E][H][2I]; dst row layout per 256-row block b: rows [b*256, b*256+128) = gate cols
// [b*128, b*128+128), rows [b*256+128, b*256+256) = up cols [b*128, b*128+128).
__global__ __launch_bounds__(256) void cvt_wgu_kernel(const float* __restrict__ in,
                                                      unsigned short* __restrict__ out) {
  __shared__ float tile[64][65];
  const int e = blockIdx.z;
  const int r0 = blockIdx.y * 64, c0 = blockIdx.x * 64;
  const int tid = threadIdx.x;
  const float* src = in + (size_t)e * HH * (2 * ID);
  const int rr = tid >> 4, c4 = tid & 15;
#pragma unroll
  for (int it = 0; it < 4; ++it) {
    const int r = it * 16 + rr;
    const float4 v = *(const float4*)(src + (size_t)(r0 + r) * (2 * ID) + c0 + c4 * 4);
    tile[r][c4 * 4 + 0] = v.x; tile[r][c4 * 4 + 1] = v.y;
    tile[r][c4 * 4 + 2] = v.z; tile[r][c4 * 4 + 3] = v.w;
  }
  __syncthreads();
  unsigned short* dst = out + (size_t)e * HH * (2 * ID);
#pragma unroll
  for (int it = 0; it < 2; ++it) {
    const int task = tid + it * 256;
    const int c = task >> 3, g = task & 7;
    const int n = c0 + c;   // source col in [0, 2I)
    const int dr = (n < ID) ? ((n >> 7) * 256 + (n & 127))
                            : (((n - ID) >> 7) * 256 + 128 + ((n - ID) & 127));
    union { unsigned short us[8]; uint4 v; } p;
#pragma unroll
    for (int j = 0; j < 8; ++j) p.us[j] = f2b(tile[g * 8 + j][c]);
    *(uint4*)(dst + (size_t)dr * HH + r0 + g * 8) = p.v;
  }
}

// ---------------- router: logits (f64 acc, parallel) + top-8 + assign ----------------
__global__ __launch_bounds__(256) void router_kernel(
    const float* __restrict__ x, const float* __restrict__ gw,
    const float* __restrict__ gb, int* __restrict__ counts,
    int* __restrict__ tok_slot, float* __restrict__ w_slot) {
  const int t = blockIdx.x;
  const int tid = threadIdx.x;
  const int e = tid & 31;
  const int c = tid >> 5;
  const float* xr = x + (size_t)t * HH;

  __shared__ double pl[8][NE];
  __shared__ float logits[NE];

  double a0 = 0.0, a1 = 0.0, a2 = 0.0, a3 = 0.0;
  const int j0 = c * 256;
#pragma unroll 4
  for (int j = 0; j < 256; j += 4) {
    const int jj = j0 + j;
    a0 = fma((double)xr[jj + 0], (double)gw[(size_t)(jj + 0) * NE + e], a0);
    a1 = fma((double)xr[jj + 1], (double)gw[(size_t)(jj + 1) * NE + e], a1);
    a2 = fma((double)xr[jj + 2], (double)gw[(size_t)(jj + 2) * NE + e], a2);
    a3 = fma((double)xr[jj + 3], (double)gw[(size_t)(jj + 3) * NE + e], a3);
  }
  pl[c][e] = (a0 + a1) + (a2 + a3);
  __syncthreads();

  if (tid < NE) {
    double s = 0.0;
    for (int cc = 0; cc < 8; ++cc) s += pl[cc][tid];
    logits[tid] = (float)s + gb[tid];
  }
  __syncthreads();

  if (tid == 0) {
    float l[NE];
    float m = -1e30f;
    for (int i = 0; i < NE; ++i) { l[i] = logits[i]; m = fmaxf(m, l[i]); }
    int sel[KTOP]; float ex[KTOP]; float s = 0.f;
    for (int k = 0; k < KTOP; ++k) {
      float best = -1e30f; int bi = 0;
      for (int i = 0; i < NE; ++i)
        if (l[i] > best) { best = l[i]; bi = i; }   // strict > : lowest index on ties (jax)
      sel[k] = bi;
      ex[k] = expf(best - m);
      s += ex[k];
      l[bi] = -1e31f;
    }
    const float inv = 1.f / s;
    for (int k = 0; k < KTOP; ++k) {
      const int ee = sel[k];
      const int pos = atomicAdd(&counts[ee], 1);
      if (pos < CAP) {
        tok_slot[ee * CAP + pos] = t;
        w_slot[ee * CAP + pos] = ex[k] * inv;
      }
    }
  }
}

// ================= 256x256 BK=64 counted-vmcnt phase-pipelined GEMMs =================
//
// Block: 512 thr = 8 waves (2 M-sub x 4 N-sub). Tile 256x256, BK=64, K-tile double-buffered.
// LDS: [2 buf][2 half(128 rows)][128*64 bf16] per matrix = 64 KB; A+B = 128 KB exactly
// (the m201-verified footprint; no other LDS in these kernels).
// Swizzle: global row chunk c (8 x 16B per 128B row) stored at LDS chunk c ^ (row&7),
// realized as pre-swizzled global SOURCE (global_load_lds dest must stay linear, rule 21);
// fragment ds_read applies the same XOR -> conflict-free.
// Phases = block-C quadrants (Qm,Qn) in order (0,0),(0,1),(1,0),(1,1); 16 MFMA/phase/wave.
// Staging: ph1 issues next tile's half-0 (4 loads/thread... 4 gload16 per wave-slot),
// ph2 next tile's half-1. Waits: vmcnt(4) end-ph1 (current tile's half-1 landed before
// ph2/ph3/ph4 read it), vmcnt(2) end-ph4 (next tile's half-0 landed before its ph1).
// Never vmcnt(0) inside the loop (T4).

#define STG_A(nb, half, k0)                                                   \
  do {                                                                        \
    gload16(A_src[(half) * 2 + 0] + (k0), &Asb[nb][half][w * 512]);           \
    gload16(A_src[(half) * 2 + 1] + (k0), &Asb[nb][half][4096 + w * 512]);    \
  } while (0)
#define STG_B(nb, half, k0)                                                   \
  do {                                                                        \
    gload16(B_src[(half) * 2 + 0] + (k0), &Bsb[nb][half][w * 512]);           \
    gload16(B_src[(half) * 2 + 1] + (k0), &Bsb[nb][half][4096 + w * 512]);    \
  } while (0)

#define MFMA16(QM, QN)                                                        \
  do {                                                                        \
    _Pragma("unroll")                                                         \
    for (int m = 0; m < 4; ++m) {                                             \
      _Pragma("unroll")                                                       \
      for (int n = 0; n < 2; ++n) {                                           \
        acc[QM][QN][m][n] = __builtin_amdgcn_mfma_f32_16x16x32_bf16(          \
            af[m][0], bf[n][0], acc[QM][QN][m][n], 0, 0, 0);                  \
        acc[QM][QN][m][n] = __builtin_amdgcn_mfma_f32_16x16x32_bf16(          \
            af[m][1], bf[n][1], acc[QM][QN][m][n], 0, 0, 0);                  \
      }                                                                       \
    }                                                                         \
  } while (0)

#define LDA(half)                                                             \
  do {                                                                        \
    _Pragma("unroll")                                                         \
    for (int m = 0; m < 4; ++m) {                                             \
      af[m][0] = *(const bf16x8*)&Asb[buf][half][(arow + m * 16) * 64 + cs0f];\
      af[m][1] = *(const bf16x8*)&Asb[buf][half][(arow + m * 16) * 64 + cs1f];\
    }                                                                         \
  } while (0)
#define LDB(half)                                                             \
  do {                                                                        \
    _Pragma("unroll")                                                         \
    for (int n = 0; n < 2; ++n) {                                             \
      bf[n][0] = *(const bf16x8*)&Bsb[buf][half][(brow + n * 16) * 64 + cs0f];\
      bf[n][1] = *(const bf16x8*)&Bsb[buf][half][(brow + n * 16) * 64 + cs1f];\
    }                                                                         \
  } while (0)

// gate_up GEMM + SiLU*mul. grid (2I/256=6, CAP/256=4, E); block 512.
__global__ __launch_bounds__(512, 2) void gu3_kernel(
    const unsigned short* __restrict__ xb, const unsigned short* __restrict__ wguT,
    const int* __restrict__ counts, const int* __restrict__ tok_slot,
    unsigned short* __restrict__ h_ws) {
  const int e = blockIdx.z, mt = blockIdx.y, nt = blockIdx.x;
  int cnt = counts[e]; cnt = cnt > CAP ? CAP : cnt;
  if (mt * 256 >= cnt) return;

  __shared__ __align__(16) unsigned short Asb[2][2][128 * 64];
  __shared__ __align__(16) unsigned short Bsb[2][2][128 * 64];

  const int tid = threadIdx.x;
  const int w = tid >> 6, lane = tid & 63;
  const int wr = w & 1, wc = w >> 1;
  const int lr = lane & 15, quad = lane >> 4;

  // staging: thread (ra, ca) stages row ra, linear chunk ca, from pre-swizzled src chunk
  const int ra = tid >> 3, ca = tid & 7;
  const int cs = (ca ^ (ra & 7)) * 8;   // (ra+64)&7 == ra&7, so valid for both row groups

  const int* tsl = tok_slot + e * CAP + mt * 256;
  const unsigned short* A_src[4];
  A_src[0] = xb + (size_t)tsl[ra] * HH + cs;
  A_src[1] = xb + (size_t)tsl[64 + ra] * HH + cs;
  A_src[2] = xb + (size_t)tsl[128 + ra] * HH + cs;
  A_src[3] = xb + (size_t)tsl[192 + ra] * HH + cs;
  const unsigned short* bb = wguT + (size_t)e * (2 * ID) * HH + (size_t)(nt * 256) * HH;
  const unsigned short* B_src[4];
  B_src[0] = bb + (size_t)ra * HH + cs;
  B_src[1] = bb + (size_t)(64 + ra) * HH + cs;
  B_src[2] = bb + (size_t)(128 + ra) * HH + cs;
  B_src[3] = bb + (size_t)(192 + ra) * HH + cs;

  // fragment reads: row = base16 + lr (base16 % 8 == 0), so row&7 == lr&7
  const int cs0f = (quad ^ (lr & 7)) * 8;
  const int cs1f = ((4 + quad) ^ (lr & 7)) * 8;
  const int arow = wr * 64 + lr;
  const int brow = wc * 32 + lr;

  f32x4 acc[2][2][4][2];
#pragma unroll
  for (int a = 0; a < 2; ++a)
#pragma unroll
    for (int b = 0; b < 2; ++b)
#pragma unroll
      for (int m = 0; m < 4; ++m)
#pragma unroll
        for (int n = 0; n < 2; ++n)
#pragma unroll
          for (int r = 0; r < 4; ++r) acc[a][b][m][n][r] = 0.f;

  // prologue: stage tile 0 fully, drain once (outside the loop only)
  STG_A(0, 0, 0); STG_B(0, 0, 0); STG_A(0, 1, 0); STG_B(0, 1, 0);
  VMCNT(0);
  SBAR();

  bf16x8 af[4][2], bf[2][2];
  for (int t = 0; t < 32; ++t) {
    const int buf = t & 1, nb = buf ^ 1;
    const int kn = (t + 1) * 64;
    const bool pf = (t + 1) < 32;
    // ---- phase 1: (Qm0,Qn0) ----
    LDA(0); LDB(0);
    if (pf) { STG_A(nb, 0, kn); STG_B(nb, 0, kn); }
    SBAR();
    __builtin_amdgcn_s_setprio(1);
    MFMA16(0, 0);
    __builtin_amdgcn_s_setprio(0);
    VMCNT(4);
    SBAR();
    // ---- phase 2: (Qm0,Qn1) ----
    LDB(1);
    if (pf) { STG_A(nb, 1, kn); STG_B(nb, 1, kn); }
    SBAR();
    __builtin_amdgcn_s_setprio(1);
    MFMA16(0, 1);
    __builtin_amdgcn_s_setprio(0);
    SBAR();
    // ---- phase 3: (Qm1,Qn0) ----
    LDA(1); LDB(0);
    SBAR();
    __builtin_amdgcn_s_setprio(1);
    MFMA16(1, 0);
    __builtin_amdgcn_s_setprio(0);
    SBAR();
    // ---- phase 4: (Qm1,Qn1) ----
    LDB(1);
    SBAR();
    __builtin_amdgcn_s_setprio(1);
    MFMA16(1, 1);
    __builtin_amdgcn_s_setprio(0);
    VMCNT(2);
    SBAR();
  }

  // epilogue: silu(gate)*up -> bf16 h.  Qn=0 frags are gate cols, Qn=1 the matching up cols.
  unsigned short* hb = h_ws + ((size_t)e * CAP + mt * 256) * ID + nt * 128;
#pragma unroll
  for (int qm = 0; qm < 2; ++qm)
#pragma unroll
    for (int m = 0; m < 4; ++m)
#pragma unroll
      for (int r = 0; r < 4; ++r) {
        const int row = qm * 128 + wr * 64 + m * 16 + quad * 4 + r;
#pragma unroll
        for (int n = 0; n < 2; ++n) {
          const float g = acc[qm][0][m][n][r], u = acc[qm][1][m][n][r];
          const float h = (g / (1.f + __expf(-g))) * u;
          hb[(size_t)row * ID + wc * 32 + n * 16 + lr] = f2b(h);
        }
      }
}

// down GEMM + weight-scale + scatter-add. grid (H/256=8, CAP/256=4, E); block 512.
__global__ __launch_bounds__(512, 2) void down3_kernel(
    const unsigned short* __restrict__ h_ws, const unsigned short* __restrict__ wdT,
    const int* __restrict__ counts, const int* __restrict__ tok_slot,
    const float* __restrict__ w_slot, float* __restrict__ out) {
  const int e = blockIdx.z, mt = blockIdx.y, nt = blockIdx.x;
  int cnt = counts[e]; cnt = cnt > CAP ? CAP : cnt;
  if (mt * 256 >= cnt) return;

  __shared__ __align__(16) unsigned short Asb[2][2][128 * 64];
  __shared__ __align__(16) unsigned short Bsb[2][2][128 * 64];

  const int tid = threadIdx.x;
  const int w = tid >> 6, lane = tid & 63;
  const int wr = w & 1, wc = w >> 1;
  const int lr = lane & 15, quad = lane >> 4;

  const int ra = tid >> 3, ca = tid & 7;
  const int cs = (ca ^ (ra & 7)) * 8;

  const unsigned short* hb = h_ws + ((size_t)e * CAP + mt * 256) * ID;
  const unsigned short* A_src[4];
  A_src[0] = hb + (size_t)ra * ID + cs;
  A_src[1] = hb + (size_t)(64 + ra) * ID + cs;
  A_src[2] = hb + (size_t)(128 + ra) * ID + cs;
  A_src[3] = hb + (size_t)(192 + ra) * ID + cs;
  const unsigned short* wb = wdT + (size_t)e * HH * ID + (size_t)(nt * 256) * ID;
  const unsigned short* B_src[4];
  B_src[0] = wb + (size_t)ra * ID + cs;
  B_src[1] = wb + (size_t)(64 + ra) * ID + cs;
  B_src[2] = wb + (size_t)(128 + ra) * ID + cs;
  B_src[3] = wb + (size_t)(192 + ra) * ID + cs;

  const int cs0f = (quad ^ (lr & 7)) * 8;
  const int cs1f = ((4 + quad) ^ (lr & 7)) * 8;
  const int arow = wr * 64 + lr;
  const int brow = wc * 32 + lr;

  f32x4 acc[2][2][4][2];
#pragma unroll
  for (int a = 0; a < 2; ++a)
#pragma unroll
    for (int b = 0; b < 2; ++b)
#pragma unroll
      for (int m = 0; m < 4; ++m)
#pragma unroll
        for (int n = 0; n < 2; ++n)
#pragma unroll
          for (int r = 0; r < 4; ++r) acc[a][b][m][n][r] = 0.f;

  STG_A(0, 0, 0); STG_B(0, 0, 0); STG_A(0, 1, 0); STG_B(0, 1, 0);
  VMCNT(0);
  SBAR();

  bf16x8 af[4][2], bf[2][2];
  for (int t = 0; t < 12; ++t) {
    const int buf = t & 1, nb = buf ^ 1;
    const int kn = (t + 1) * 64;
    const bool pf = (t + 1) < 12;
    // ---- phase 1 ----
    LDA(0); LDB(0);
    if (pf) { STG_A(nb, 0, kn); STG_B(nb, 0, kn); }
    SBAR();
    __builtin_amdgcn_s_setprio(1);
    MFMA16(0, 0);
    __builtin_amdgcn_s_setprio(0);
    VMCNT(4);
    SBAR();
    // ---- phase 2 ----
    LDB(1);
    if (pf) { STG_A(nb, 1, kn); STG_B(nb, 1, kn); }
    SBAR();
    __builtin_amdgcn_s_setprio(1);
    MFMA16(0, 1);
    __builtin_amdgcn_s_setprio(0);
    SBAR();
    // ---- phase 3 ----
    LDA(1); LDB(0);
    SBAR();
    __builtin_amdgcn_s_setprio(1);
    MFMA16(1, 0);
    __builtin_amdgcn_s_setprio(0);
    SBAR();
    // ---- phase 4 ----
    LDB(1);
    SBAR();
    __builtin_amdgcn_s_setprio(1);
    MFMA16(1, 1);
    __builtin_amdgcn_s_setprio(0);
    VMCNT(2);
    SBAR();
  }

  const int* tsl = tok_slot + e * CAP + mt * 256;
  const float* wsl = w_slot + e * CAP + mt * 256;
#pragma unroll
  for (int qm = 0; qm < 2; ++qm)
#pragma unroll
    for (int m = 0; m < 4; ++m)
#pragma unroll
      for (int r = 0; r < 4; ++r) {
        const int row = qm * 128 + wr * 64 + m * 16 + quad * 4 + r;
        const float wgt = wsl[row];
        if (wgt != 0.f) {
          const int tk = tsl[row];
          float* op = out + (size_t)tk * HH + nt * 256;
#pragma unroll
          for (int qn = 0; qn < 2; ++qn)
#pragma unroll
            for (int n = 0; n < 2; ++n)
              atomicAdd(op + qn * 128 + wc * 32 + n * 16 + lr,
                        acc[qm][qn][m][n][r] * wgt);
        }
      }
}

// ================= LEGACY PATH (fallback if ws too small): convert-in-GEMM =================

__global__ __launch_bounds__(256) void gu_kernel(
    const unsigned short* __restrict__ xb, const float* __restrict__ wgu,
    const int* __restrict__ counts, const int* __restrict__ tok_slot,
    unsigned short* __restrict__ h_ws) {
  const int e = blockIdx.z, mt = blockIdx.y, nt = blockIdx.x;
  int cnt = counts[e]; cnt = cnt > CAP ? CAP : cnt;
  if (mt * 128 >= cnt) return;

  __shared__ __align__(16) unsigned short As[128][40];
  __shared__ __align__(16) unsigned short Bg[64][40];
  __shared__ __align__(16) unsigned short Bu[64][40];
  __shared__ int toks[128];

  const int tid = threadIdx.x;
  if (tid < 128) toks[tid] = tok_slot[e * CAP + mt * 128 + tid];
  __syncthreads();

  const float* wg = wgu + (size_t)e * HH * (2 * ID) + nt * 64;
  const float* wu = wg + ID;

  const int wid = tid >> 6, lane = tid & 63;
  const int wm = wid & 1, wn = wid >> 1;
  const int lr = lane & 15, quad = lane >> 4;

  f32x4 accg[4][2], accu[4][2];
  for (int s = 0; s < 4; ++s)
    for (int t = 0; t < 2; ++t)
      for (int r = 0; r < 4; ++r) { accg[s][t][r] = 0.f; accu[s][t][r] = 0.f; }

  for (int k0 = 0; k0 < HH; k0 += 32) {
#pragma unroll
    for (int it = 0; it < 2; ++it) {
      const int task = tid + it * 256;
      const int row = task >> 2, cg = task & 3;
      const uint4 v = *(const uint4*)(xb + (size_t)toks[row] * HH + k0 + cg * 8);
      *(uint4*)&As[row][cg * 8] = v;
    }
#pragma unroll
    for (int it = 0; it < 2; ++it) {
      const int task = tid + it * 256;
      const int k = task >> 4, cg = task & 15;
      const size_t off = (size_t)(k0 + k) * (2 * ID) + cg * 4;
      const float4 vg = *(const float4*)(wg + off);
      const float4 vu = *(const float4*)(wu + off);
      Bg[cg * 4 + 0][k] = f2b(vg.x); Bg[cg * 4 + 1][k] = f2b(vg.y);
      Bg[cg * 4 + 2][k] = f2b(vg.z); Bg[cg * 4 + 3][k] = f2b(vg.w);
      Bu[cg * 4 + 0][k] = f2b(vu.x); Bu[cg * 4 + 1][k] = f2b(vu.y);
      Bu[cg * 4 + 2][k] = f2b(vu.z); Bu[cg * 4 + 3][k] = f2b(vu.w);
    }
    __syncthreads();
    bf16x8 af[4];
#pragma unroll
    for (int s = 0; s < 4; ++s)
      af[s] = *(const bf16x8*)&As[wm * 64 + s * 16 + lr][quad * 8];
#pragma unroll
    for (int t = 0; t < 2; ++t) {
      const bf16x8 bg = *(const bf16x8*)&Bg[wn * 32 + t * 16 + lr][quad * 8];
      const bf16x8 bu = *(const bf16x8*)&Bu[wn * 32 + t * 16 + lr][quad * 8];
#pragma unroll
      for (int s = 0; s < 4; ++s) {
        accg[s][t] = __builtin_amdgcn_mfma_f32_16x16x32_bf16(af[s], bg, accg[s][t], 0, 0, 0);
        accu[s][t] = __builtin_amdgcn_mfma_f32_16x16x32_bf16(af[s], bu, accu[s][t], 0, 0, 0);
      }
    }
    __syncthreads();
  }

  unsigned short* hb = h_ws + (size_t)(e * CAP + mt * 128) * ID + nt * 64;
#pragma unroll
  for (int s = 0; s < 4; ++s)
#pragma unroll
    for (int t = 0; t < 2; ++t)
#pragma unroll
      for (int r = 0; r < 4; ++r) {
        const int row = wm * 64 + s * 16 + quad * 4 + r;
        const int col = wn * 32 + t * 16 + lr;
        const float g = accg[s][t][r], u = accu[s][t][r];
        const float h = (g / (1.f + __expf(-g))) * u;
        hb[(size_t)row * ID + col] = f2b(h);
      }
}

__global__ __launch_bounds__(256) void down_kernel(
    const unsigned short* __restrict__ h_ws, const float* __restrict__ wd,
    const int* __restrict__ counts, const int* __restrict__ tok_slot,
    const float* __restrict__ w_slot, float* __restrict__ out) {
  const int e = blockIdx.z, mt = blockIdx.y;
  const int nb = blockIdx.x * 128;
  int cnt = counts[e]; cnt = cnt > CAP ? CAP : cnt;
  if (mt * 128 >= cnt) return;

  __shared__ __align__(16) unsigned short As[128][40];
  __shared__ __align__(16) unsigned short Bs[128][40];
  __shared__ int toks[128];
  __shared__ float wr[128];

  const int tid = threadIdx.x;
  if (tid < 128) {
    toks[tid] = tok_slot[e * CAP + mt * 128 + tid];
    wr[tid] = w_slot[e * CAP + mt * 128 + tid];
  }

  const unsigned short* hb = h_ws + (size_t)(e * CAP + mt * 128) * ID;
  const float* wb = wd + (size_t)e * ID * HH + nb;

  const int wid = tid >> 6, lane = tid & 63;
  const int wm = wid & 1, wn = wid >> 1;
  const int lr = lane & 15, quad = lane >> 4;

  f32x4 acc[4][4];
  for (int s = 0; s < 4; ++s)
    for (int t = 0; t < 4; ++t)
      for (int r = 0; r < 4; ++r) acc[s][t][r] = 0.f;

  for (int k0 = 0; k0 < ID; k0 += 32) {
#pragma unroll
    for (int it = 0; it < 2; ++it) {
      const int task = tid + it * 256;
      const int row = task >> 2, cg = task & 3;
      const uint4 v = *(const uint4*)(hb + (size_t)row * ID + k0 + cg * 8);
      *(uint4*)&As[row][cg * 8] = v;
    }
#pragma unroll
    for (int it = 0; it < 4; ++it) {
      const int task = tid + it * 256;
      const int k = task >> 5, cg = task & 31;
      const float4 v = *(const float4*)(wb + (size_t)(k0 + k) * HH + cg * 4);
      Bs[cg * 4 + 0][k] = f2b(v.x); Bs[cg * 4 + 1][k] = f2b(v.y);
      Bs[cg * 4 + 2][k] = f2b(v.z); Bs[cg * 4 + 3][k] = f2b(v.w);
    }
    __syncthreads();
    bf16x8 af[4], bfr[4];
#pragma unroll
    for (int s = 0; s < 4; ++s)
      af[s] = *(const bf16x8*)&As[wm * 64 + s * 16 + lr][quad * 8];
#pragma unroll
    for (int t = 0; t < 4; ++t)
      bfr[t] = *(const bf16x8*)&Bs[wn * 64 + t * 16 + lr][quad * 8];
#pragma unroll
    for (int s = 0; s < 4; ++s)
#pragma unroll
      for (int t = 0; t < 4; ++t)
        acc[s][t] = __builtin_amdgcn_mfma_f32_16x16x32_bf16(af[s], bfr[t], acc[s][t], 0, 0, 0);
    __syncthreads();
  }

#pragma unroll
  for (int s = 0; s < 4; ++s) {
#pragma unroll
    for (int r = 0; r < 4; ++r) {
      const int row = wm * 64 + s * 16 + quad * 4 + r;
      const float w = wr[row];
      if (w != 0.f) {
        const int tk = toks[row];
        float* op = out + (size_t)tk * HH + nb + wn * 64 + lr;
#pragma unroll
        for (int t = 0; t < 4; ++t)
          atomicAdd(op + t * 16, acc[s][t][r] * w);
      }
    }
  }
}

extern "C" void kernel_launch(void* const* d_in, const int* in_sizes, int n_in,
                              void* d_out, int out_size, void* d_ws, size_t ws_size,
                              hipStream_t stream) {
  const float* x   = (const float*)d_in[0];
  const float* gw  = (const float*)d_in[1];
  const float* gb  = (const float*)d_in[2];
  const float* wgu = (const float*)d_in[3];
  const float* wd  = (const float*)d_in[4];
  float* out = (float*)d_out;

  char* ws = (char*)d_ws;
  int*   counts   = (int*)ws;                                       // 256 B
  int*   tok_slot = (int*)(ws + 256);                               // 131072 B
  float* w_slot   = (float*)(ws + 256 + 131072);                    // 131072 B
  unsigned short* xb   = (unsigned short*)(ws + 262656);            // 8 MB
  unsigned short* h_ws = (unsigned short*)(ws + 8651264);           // 50.3 MB
  unsigned short* wguT = (unsigned short*)(ws + 58982912);          // 201.3 MB
  unsigned short* wdT  = (unsigned short*)(ws + 260309504);         // 100.7 MB
  const size_t NEED = 360972800ULL;

  hipMemsetAsync(d_ws, 0, 262400, stream);                          // counts + slots
  hipMemsetAsync(d_out, 0, (size_t)out_size * sizeof(float), stream);

  cvt_x_kernel<<<dim3((TT * HH) / (256 * 8)), dim3(256), 0, stream>>>(x, xb);
  router_kernel<<<dim3(TT), dim3(256), 0, stream>>>(x, gw, gb, counts, tok_slot, w_slot);

  if (ws_size >= NEED) {
    cvt_wgu_kernel<<<dim3((2 * ID) / 64, HH / 64, NE), dim3(256), 0, stream>>>(wgu, wguT);
    cvt_w_kernel<<<dim3(HH / 64, ID / 64, NE), dim3(256), 0, stream>>>(wd, wdT, ID, HH);
    gu3_kernel<<<dim3((2 * ID) / 256, CAP / 256, NE), dim3(512), 0, stream>>>(
        xb, wguT, counts, tok_slot, h_ws);
    down3_kernel<<<dim3(HH / 256, CAP / 256, NE), dim3(512), 0, stream>>>(
        h_ws, wdT, counts, tok_slot, w_slot, out);
  } else {
    gu_kernel<<<dim3(ID / 64, CAP / 128, NE), dim3(256), 0, stream>>>(xb, wgu, counts, tok_slot, h_ws);
    down_kernel<<<dim3(HH / 128, CAP / 128, NE), dim3(256), 0, stream>>>(h_ws, wd, counts, tok_slot, w_slot, out);
  }
}

// Round 3
// 1121.611 us; speedup vs baseline: 1.1299x; 1.1299x over previous
//
#include <hip/hip_runtime.h>
#include <math.h>

#define TT 2048
#define HH 2048
#define ID 768
#define NE 32
#define KTOP 8
#define CAP 1024

typedef short bf16x8 __attribute__((ext_vector_type(8)));
typedef float f32x4 __attribute__((ext_vector_type(4)));

__device__ __forceinline__ unsigned short f2b(float f) {
  unsigned int u = __builtin_bit_cast(unsigned int, f);
  u += 0x7fff + ((u >> 16) & 1);   // round-to-nearest-even
  return (unsigned short)(u >> 16);
}

__device__ __forceinline__ void gload16(const unsigned short* g, void* l) {
  __builtin_amdgcn_global_load_lds(
      (const __attribute__((address_space(1))) unsigned int*)g,
      (__attribute__((address_space(3))) unsigned int*)l, 16, 0, 0);
}

// ---------------- x -> bf16 pre-convert ----------------
__global__ __launch_bounds__(256) void cvt_x_kernel(const float* __restrict__ x,
                                                    unsigned short* __restrict__ xb) {
  const size_t i = ((size_t)blockIdx.x * 256 + threadIdx.x) * 8;
  const float4 a = *(const float4*)(x + i);
  const float4 b = *(const float4*)(x + i + 4);
  union { unsigned short us[8]; uint4 v; } p;
  p.us[0] = f2b(a.x); p.us[1] = f2b(a.y); p.us[2] = f2b(a.z); p.us[3] = f2b(a.w);
  p.us[4] = f2b(b.x); p.us[5] = f2b(b.y); p.us[6] = f2b(b.z); p.us[7] = f2b(b.w);
  *(uint4*)(xb + i) = p.v;
}

// ---------------- weight transpose+convert: in [E][R][C] f32 -> out [E][C][R] bf16 ----------------
__global__ __launch_bounds__(256) void cvt_w_kernel(const float* __restrict__ in,
                                                    unsigned short* __restrict__ out,
                                                    int R, int C) {
  __shared__ float tile[64][65];
  const int e = blockIdx.z;
  const int r0 = blockIdx.y * 64, c0 = blockIdx.x * 64;
  const int tid = threadIdx.x;
  const float* src = in + (size_t)e * R * C;
  const int rr = tid >> 4, c4 = tid & 15;
#pragma unroll
  for (int it = 0; it < 4; ++it) {
    const int r = it * 16 + rr;
    const float4 v = *(const float4*)(src + (size_t)(r0 + r) * C + c0 + c4 * 4);
    tile[r][c4 * 4 + 0] = v.x; tile[r][c4 * 4 + 1] = v.y;
    tile[r][c4 * 4 + 2] = v.z; tile[r][c4 * 4 + 3] = v.w;
  }
  __syncthreads();
  unsigned short* dst = out + (size_t)e * R * C;
#pragma unroll
  for (int it = 0; it < 2; ++it) {
    const int task = tid + it * 256;
    const int c = task >> 3, g = task & 7;
    union { unsigned short us[8]; uint4 v; } p;
#pragma unroll
    for (int j = 0; j < 8; ++j) p.us[j] = f2b(tile[g * 8 + j][c]);
    *(uint4*)(dst + (size_t)(c0 + c) * R + r0 + g * 8) = p.v;
  }
}

// ---------------- router: logits (f64 acc, parallel) + top-8 + assign + inverse map ----------------
__global__ __launch_bounds__(256) void router_kernel(
    const float* __restrict__ x, const float* __restrict__ gw,
    const float* __restrict__ gb, int* __restrict__ counts,
    int* __restrict__ tok_slot, float* __restrict__ w_slot,
    int* __restrict__ inv) {
  const int t = blockIdx.x;
  const int tid = threadIdx.x;
  const int e = tid & 31;
  const int c = tid >> 5;
  const float* xr = x + (size_t)t * HH;

  __shared__ double pl[8][NE];
  __shared__ float logits[NE];

  double a0 = 0.0, a1 = 0.0, a2 = 0.0, a3 = 0.0;
  const int j0 = c * 256;
#pragma unroll 4
  for (int j = 0; j < 256; j += 4) {
    const int jj = j0 + j;
    a0 = fma((double)xr[jj + 0], (double)gw[(size_t)(jj + 0) * NE + e], a0);
    a1 = fma((double)xr[jj + 1], (double)gw[(size_t)(jj + 1) * NE + e], a1);
    a2 = fma((double)xr[jj + 2], (double)gw[(size_t)(jj + 2) * NE + e], a2);
    a3 = fma((double)xr[jj + 3], (double)gw[(size_t)(jj + 3) * NE + e], a3);
  }
  pl[c][e] = (a0 + a1) + (a2 + a3);
  __syncthreads();

  if (tid < NE) {
    double s = 0.0;
    for (int cc = 0; cc < 8; ++cc) s += pl[cc][tid];
    logits[tid] = (float)s + gb[tid];
  }
  __syncthreads();

  if (tid == 0) {
    float l[NE];
    float m = -1e30f;
    for (int i = 0; i < NE; ++i) { l[i] = logits[i]; m = fmaxf(m, l[i]); }
    int sel[KTOP]; float ex[KTOP]; float s = 0.f;
    for (int k = 0; k < KTOP; ++k) {
      float best = -1e30f; int bi = 0;
      for (int i = 0; i < NE; ++i)
        if (l[i] > best) { best = l[i]; bi = i; }   // strict > : lowest index on ties (jax)
      sel[k] = bi;
      ex[k] = expf(best - m);
      s += ex[k];
      l[bi] = -1e31f;
    }
    const float inv_s = 1.f / s;
    for (int k = 0; k < KTOP; ++k) {
      const int ee = sel[k];
      const int pos = atomicAdd(&counts[ee], 1);
      if (pos < CAP) {
        tok_slot[ee * CAP + pos] = t;
        w_slot[ee * CAP + pos] = ex[k] * inv_s;
        inv[t * KTOP + k] = ee * CAP + pos;
      } else {
        inv[t * KTOP + k] = -1;
      }
    }
  }
}

// ================= 128x128-tile BK=64 2-barrier GEMMs (m97 structure, swizzled LDS) =================
//
// 256 thr = 4 waves (2 M-sub x 2 N-sub). 128-row A tile, BK=64 -> 128 B rows in LDS.
// Swizzle (mandatory at 128 B rows, else 16-way bank conflict): global row chunk c
// (8 x 16B per row) stored at LDS chunk c ^ (row&7), realized by pre-swizzling the
// global SOURCE column (global_load_lds dest must stay linear); fragment ds_reads
// apply the same XOR. K accumulation order identical to BK=32 version (bit-identical).

// gate_up GEMM + SiLU*mul. grid (ID/64=12, CAP/128=8, E); block 256.
__global__ __launch_bounds__(256) void gu4_kernel(
    const unsigned short* __restrict__ xb, const unsigned short* __restrict__ wguT,
    const int* __restrict__ counts, const int* __restrict__ tok_slot,
    unsigned short* __restrict__ h_ws) {
  const int e = blockIdx.z, mt = blockIdx.y, nt = blockIdx.x;
  int cnt = counts[e]; cnt = cnt > CAP ? CAP : cnt;
  if (mt * 128 >= cnt) return;

  __shared__ __align__(16) unsigned short As[128 * 64];
  __shared__ __align__(16) unsigned short Bg[64 * 64];
  __shared__ __align__(16) unsigned short Bu[64 * 64];
  __shared__ int toks[128];

  const int tid = threadIdx.x;
  if (tid < 128) toks[tid] = tok_slot[e * CAP + mt * 128 + tid];
  __syncthreads();

  const int w = tid >> 6, lane = tid & 63;
  const int wm = w & 1, wn = w >> 1;
  const int lr = lane & 15, quad = lane >> 4;

  // staging: thread covers chunk (i*256 + tid); row = i*32 + (tid>>3), chunk col = tid&7.
  // source column pre-swizzled by row&7 (= (tid>>3)&7, invariant across i since i*32 % 8 == 0).
  const int ra = tid >> 3;
  const int sw = ((tid & 7) ^ (ra & 7)) * 8;

  const unsigned short* srcA[4];
#pragma unroll
  for (int i = 0; i < 4; ++i)
    srcA[i] = xb + (size_t)toks[i * 32 + ra] * HH + sw;
  const unsigned short* bgp = wguT + (size_t)e * (2 * ID) * HH + (size_t)(nt * 64) * HH;
  const unsigned short* bup = bgp + (size_t)ID * HH;
  const unsigned short* srcBg[2];
  const unsigned short* srcBu[2];
#pragma unroll
  for (int i = 0; i < 2; ++i) {
    srcBg[i] = bgp + (size_t)(i * 32 + ra) * HH + sw;
    srcBu[i] = bup + (size_t)(i * 32 + ra) * HH + sw;
  }

  // fragment-read swizzled chunk offsets: row&7 == lr&7 (row = 16-aligned base + lr)
  const int cs0f = ((quad) ^ (lr & 7)) * 8;        // k-slice 0: global chunk quad
  const int cs1f = ((4 + quad) ^ (lr & 7)) * 8;    // k-slice 1: global chunk 4+quad

  f32x4 accg[4][2], accu[4][2];
#pragma unroll
  for (int s = 0; s < 4; ++s)
#pragma unroll
    for (int t = 0; t < 2; ++t)
#pragma unroll
      for (int r = 0; r < 4; ++r) { accg[s][t][r] = 0.f; accu[s][t][r] = 0.f; }

  for (int k0 = 0; k0 < HH; k0 += 64) {
#pragma unroll
    for (int i = 0; i < 4; ++i)
      gload16(srcA[i] + k0, (char*)As + i * 4096 + w * 1024);
#pragma unroll
    for (int i = 0; i < 2; ++i)
      gload16(srcBg[i] + k0, (char*)Bg + i * 4096 + w * 1024);
#pragma unroll
    for (int i = 0; i < 2; ++i)
      gload16(srcBu[i] + k0, (char*)Bu + i * 4096 + w * 1024);
    __syncthreads();
#pragma unroll
    for (int sl = 0; sl < 2; ++sl) {
      const int cf = sl ? cs1f : cs0f;
      bf16x8 af[4], bg[2], bu[2];
#pragma unroll
      for (int s = 0; s < 4; ++s)
        af[s] = *(const bf16x8*)&As[(wm * 64 + s * 16 + lr) * 64 + cf];
#pragma unroll
      for (int t = 0; t < 2; ++t) {
        bg[t] = *(const bf16x8*)&Bg[(wn * 32 + t * 16 + lr) * 64 + cf];
        bu[t] = *(const bf16x8*)&Bu[(wn * 32 + t * 16 + lr) * 64 + cf];
      }
#pragma unroll
      for (int t = 0; t < 2; ++t)
#pragma unroll
        for (int s = 0; s < 4; ++s) {
          accg[s][t] = __builtin_amdgcn_mfma_f32_16x16x32_bf16(af[s], bg[t], accg[s][t], 0, 0, 0);
          accu[s][t] = __builtin_amdgcn_mfma_f32_16x16x32_bf16(af[s], bu[t], accu[s][t], 0, 0, 0);
        }
    }
    __syncthreads();
  }

  unsigned short* hb = h_ws + (size_t)(e * CAP + mt * 128) * ID + nt * 64;
#pragma unroll
  for (int s = 0; s < 4; ++s)
#pragma unroll
    for (int t = 0; t < 2; ++t)
#pragma unroll
      for (int r = 0; r < 4; ++r) {
        const int row = wm * 64 + s * 16 + quad * 4 + r;
        const int col = wn * 32 + t * 16 + lr;
        const float g = accg[s][t][r], u = accu[s][t][r];
        const float h = (g / (1.f + __expf(-g))) * u;
        hb[(size_t)row * ID + col] = f2b(h);
      }
}

// down GEMM + weight-scale -> dense y_ws (no atomics). grid (H/128=16, CAP/128=8, E); block 256.
__global__ __launch_bounds__(256) void down4_kernel(
    const unsigned short* __restrict__ h_ws, const unsigned short* __restrict__ wdT,
    const int* __restrict__ counts, const float* __restrict__ w_slot,
    float* __restrict__ y_ws) {
  const int e = blockIdx.z, mt = blockIdx.y;
  const int nb = blockIdx.x * 128;
  int cnt = counts[e]; cnt = cnt > CAP ? CAP : cnt;
  if (mt * 128 >= cnt) return;

  __shared__ __align__(16) unsigned short As[128 * 64];
  __shared__ __align__(16) unsigned short Bs[128 * 64];
  __shared__ float wr[128];

  const int tid = threadIdx.x;
  if (tid < 128) wr[tid] = w_slot[e * CAP + mt * 128 + tid];

  const int w = tid >> 6, lane = tid & 63;
  const int wm = w & 1, wn = w >> 1;
  const int lr = lane & 15, quad = lane >> 4;

  const int ra = tid >> 3;
  const int sw = ((tid & 7) ^ (ra & 7)) * 8;

  const unsigned short* hb = h_ws + (size_t)(e * CAP + mt * 128) * ID;
  const unsigned short* wb = wdT + (size_t)e * HH * ID + (size_t)nb * ID;
  const unsigned short* srcA[4];
  const unsigned short* srcB[4];
#pragma unroll
  for (int i = 0; i < 4; ++i) {
    srcA[i] = hb + (size_t)(i * 32 + ra) * ID + sw;
    srcB[i] = wb + (size_t)(i * 32 + ra) * ID + sw;
  }

  const int cs0f = ((quad) ^ (lr & 7)) * 8;
  const int cs1f = ((4 + quad) ^ (lr & 7)) * 8;

  f32x4 acc[4][4];
#pragma unroll
  for (int s = 0; s < 4; ++s)
#pragma unroll
    for (int t = 0; t < 4; ++t)
#pragma unroll
      for (int r = 0; r < 4; ++r) acc[s][t][r] = 0.f;

  for (int k0 = 0; k0 < ID; k0 += 64) {
#pragma unroll
    for (int i = 0; i < 4; ++i)
      gload16(srcA[i] + k0, (char*)As + i * 4096 + w * 1024);
#pragma unroll
    for (int i = 0; i < 4; ++i)
      gload16(srcB[i] + k0, (char*)Bs + i * 4096 + w * 1024);
    __syncthreads();
#pragma unroll
    for (int sl = 0; sl < 2; ++sl) {
      const int cf = sl ? cs1f : cs0f;
      bf16x8 af[4], bfr[4];
#pragma unroll
      for (int s = 0; s < 4; ++s)
        af[s] = *(const bf16x8*)&As[(wm * 64 + s * 16 + lr) * 64 + cf];
#pragma unroll
      for (int t = 0; t < 4; ++t)
        bfr[t] = *(const bf16x8*)&Bs[(wn * 64 + t * 16 + lr) * 64 + cf];
#pragma unroll
      for (int s = 0; s < 4; ++s)
#pragma unroll
        for (int t = 0; t < 4; ++t)
          acc[s][t] = __builtin_amdgcn_mfma_f32_16x16x32_bf16(af[s], bfr[t], acc[s][t], 0, 0, 0);
    }
    __syncthreads();
  }

  // epilogue: plain weighted stores to dense per-slot buffer
  const size_t slot0 = (size_t)e * CAP + mt * 128;
#pragma unroll
  for (int s = 0; s < 4; ++s) {
#pragma unroll
    for (int r = 0; r < 4; ++r) {
      const int row = wm * 64 + s * 16 + quad * 4 + r;
      const float wgt = wr[row];
      if (wgt != 0.f) {
        float* op = y_ws + (slot0 + row) * HH + nb + wn * 64 + lr;
#pragma unroll
        for (int t = 0; t < 4; ++t)
          op[t * 16] = acc[s][t][r] * wgt;
      }
    }
  }
}

// ---------------- combine: out[t] = sum_k y_ws[inv[t][k]] ----------------
__global__ __launch_bounds__(256) void combine_kernel(
    const float* __restrict__ y_ws, const int* __restrict__ inv,
    float* __restrict__ out) {
  const int t = blockIdx.x;
  const int c = threadIdx.x;   // col group of 8 floats
  int sl[KTOP];
#pragma unroll
  for (int k = 0; k < KTOP; ++k) sl[k] = inv[t * KTOP + k];
  float4 s0 = {0.f, 0.f, 0.f, 0.f}, s1 = {0.f, 0.f, 0.f, 0.f};
#pragma unroll
  for (int k = 0; k < KTOP; ++k) {
    if (sl[k] >= 0) {
      const float* yr = y_ws + (size_t)sl[k] * HH + c * 8;
      const float4 a = *(const float4*)yr;
      const float4 b = *(const float4*)(yr + 4);
      s0.x += a.x; s0.y += a.y; s0.z += a.z; s0.w += a.w;
      s1.x += b.x; s1.y += b.y; s1.z += b.z; s1.w += b.w;
    }
  }
  float* op = out + (size_t)t * HH + c * 8;
  *(float4*)op = s0;
  *(float4*)(op + 4) = s1;
}

// ================= LEGACY PATH (fallback if ws too small): convert-in-GEMM + atomics =================

__global__ __launch_bounds__(256) void gu_kernel(
    const unsigned short* __restrict__ xb, const float* __restrict__ wgu,
    const int* __restrict__ counts, const int* __restrict__ tok_slot,
    unsigned short* __restrict__ h_ws) {
  const int e = blockIdx.z, mt = blockIdx.y, nt = blockIdx.x;
  int cnt = counts[e]; cnt = cnt > CAP ? CAP : cnt;
  if (mt * 128 >= cnt) return;

  __shared__ __align__(16) unsigned short As[128][40];
  __shared__ __align__(16) unsigned short Bg[64][40];
  __shared__ __align__(16) unsigned short Bu[64][40];
  __shared__ int toks[128];

  const int tid = threadIdx.x;
  if (tid < 128) toks[tid] = tok_slot[e * CAP + mt * 128 + tid];
  __syncthreads();

  const float* wg = wgu + (size_t)e * HH * (2 * ID) + nt * 64;
  const float* wu = wg + ID;

  const int wid = tid >> 6, lane = tid & 63;
  const int wm = wid & 1, wn = wid >> 1;
  const int lr = lane & 15, quad = lane >> 4;

  f32x4 accg[4][2], accu[4][2];
  for (int s = 0; s < 4; ++s)
    for (int t = 0; t < 2; ++t)
      for (int r = 0; r < 4; ++r) { accg[s][t][r] = 0.f; accu[s][t][r] = 0.f; }

  for (int k0 = 0; k0 < HH; k0 += 32) {
#pragma unroll
    for (int it = 0; it < 2; ++it) {
      const int task = tid + it * 256;
      const int row = task >> 2, cg = task & 3;
      const uint4 v = *(const uint4*)(xb + (size_t)toks[row] * HH + k0 + cg * 8);
      *(uint4*)&As[row][cg * 8] = v;
    }
#pragma unroll
    for (int it = 0; it < 2; ++it) {
      const int task = tid + it * 256;
      const int k = task >> 4, cg = task & 15;
      const size_t off = (size_t)(k0 + k) * (2 * ID) + cg * 4;
      const float4 vg = *(const float4*)(wg + off);
      const float4 vu = *(const float4*)(wu + off);
      Bg[cg * 4 + 0][k] = f2b(vg.x); Bg[cg * 4 + 1][k] = f2b(vg.y);
      Bg[cg * 4 + 2][k] = f2b(vg.z); Bg[cg * 4 + 3][k] = f2b(vg.w);
      Bu[cg * 4 + 0][k] = f2b(vu.x); Bu[cg * 4 + 1][k] = f2b(vu.y);
      Bu[cg * 4 + 2][k] = f2b(vu.z); Bu[cg * 4 + 3][k] = f2b(vu.w);
    }
    __syncthreads();
    bf16x8 af[4];
#pragma unroll
    for (int s = 0; s < 4; ++s)
      af[s] = *(const bf16x8*)&As[wm * 64 + s * 16 + lr][quad * 8];
#pragma unroll
    for (int t = 0; t < 2; ++t) {
      const bf16x8 bg = *(const bf16x8*)&Bg[wn * 32 + t * 16 + lr][quad * 8];
      const bf16x8 bu = *(const bf16x8*)&Bu[wn * 32 + t * 16 + lr][quad * 8];
#pragma unroll
      for (int s = 0; s < 4; ++s) {
        accg[s][t] = __builtin_amdgcn_mfma_f32_16x16x32_bf16(af[s], bg, accg[s][t], 0, 0, 0);
        accu[s][t] = __builtin_amdgcn_mfma_f32_16x16x32_bf16(af[s], bu, accu[s][t], 0, 0, 0);
      }
    }
    __syncthreads();
  }

  unsigned short* hb = h_ws + (size_t)(e * CAP + mt * 128) * ID + nt * 64;
#pragma unroll
  for (int s = 0; s < 4; ++s)
#pragma unroll
    for (int t = 0; t < 2; ++t)
#pragma unroll
      for (int r = 0; r < 4; ++r) {
        const int row = wm * 64 + s * 16 + quad * 4 + r;
        const int col = wn * 32 + t * 16 + lr;
        const float g = accg[s][t][r], u = accu[s][t][r];
        const float h = (g / (1.f + __expf(-g))) * u;
        hb[(size_t)row * ID + col] = f2b(h);
      }
}

__global__ __launch_bounds__(256) void down_kernel(
    const unsigned short* __restrict__ h_ws, const float* __restrict__ wd,
    const int* __restrict__ counts, const int* __restrict__ tok_slot,
    const float* __restrict__ w_slot, float* __restrict__ out) {
  const int e = blockIdx.z, mt = blockIdx.y;
  const int nb = blockIdx.x * 128;
  int cnt = counts[e]; cnt = cnt > CAP ? CAP : cnt;
  if (mt * 128 >= cnt) return;

  __shared__ __align__(16) unsigned short As[128][40];
  __shared__ __align__(16) unsigned short Bs[128][40];
  __shared__ int toks[128];
  __shared__ float wr[128];

  const int tid = threadIdx.x;
  if (tid < 128) {
    toks[tid] = tok_slot[e * CAP + mt * 128 + tid];
    wr[tid] = w_slot[e * CAP + mt * 128 + tid];
  }

  const unsigned short* hb = h_ws + (size_t)(e * CAP + mt * 128) * ID;
  const float* wb = wd + (size_t)e * ID * HH + nb;

  const int wid = tid >> 6, lane = tid & 63;
  const int wm = wid & 1, wn = wid >> 1;
  const int lr = lane & 15, quad = lane >> 4;

  f32x4 acc[4][4];
  for (int s = 0; s < 4; ++s)
    for (int t = 0; t < 4; ++t)
      for (int r = 0; r < 4; ++r) acc[s][t][r] = 0.f;

  for (int k0 = 0; k0 < ID; k0 += 32) {
#pragma unroll
    for (int it = 0; it < 2; ++it) {
      const int task = tid + it * 256;
      const int row = task >> 2, cg = task & 3;
      const uint4 v = *(const uint4*)(hb + (size_t)row * ID + k0 + cg * 8);
      *(uint4*)&As[row][cg * 8] = v;
    }
#pragma unroll
    for (int it = 0; it < 4; ++it) {
      const int task = tid + it * 256;
      const int k = task >> 5, cg = task & 31;
      const float4 v = *(const float4*)(wb + (size_t)(k0 + k) * HH + cg * 4);
      Bs[cg * 4 + 0][k] = f2b(v.x); Bs[cg * 4 + 1][k] = f2b(v.y);
      Bs[cg * 4 + 2][k] = f2b(v.z); Bs[cg * 4 + 3][k] = f2b(v.w);
    }
    __syncthreads();
    bf16x8 af[4], bfr[4];
#pragma unroll
    for (int s = 0; s < 4; ++s)
      af[s] = *(const bf16x8*)&As[wm * 64 + s * 16 + lr][quad * 8];
#pragma unroll
    for (int t = 0; t < 4; ++t)
      bfr[t] = *(const bf16x8*)&Bs[wn * 64 + t * 16 + lr][quad * 8];
#pragma unroll
    for (int s = 0; s < 4; ++s)
#pragma unroll
      for (int t = 0; t < 4; ++t)
        acc[s][t] = __builtin_amdgcn_mfma_f32_16x16x32_bf16(af[s], bfr[t], acc[s][t], 0, 0, 0);
    __syncthreads();
  }

#pragma unroll
  for (int s = 0; s < 4; ++s) {
#pragma unroll
    for (int r = 0; r < 4; ++r) {
      const int row = wm * 64 + s * 16 + quad * 4 + r;
      const float w = wr[row];
      if (w != 0.f) {
        const int tk = toks[row];
        float* op = out + (size_t)tk * HH + nb + wn * 64 + lr;
#pragma unroll
        for (int t = 0; t < 4; ++t)
          atomicAdd(op + t * 16, acc[s][t][r] * w);
      }
    }
  }
}

extern "C" void kernel_launch(void* const* d_in, const int* in_sizes, int n_in,
                              void* d_out, int out_size, void* d_ws, size_t ws_size,
                              hipStream_t stream) {
  const float* x   = (const float*)d_in[0];
  const float* gw  = (const float*)d_in[1];
  const float* gb  = (const float*)d_in[2];
  const float* wgu = (const float*)d_in[3];
  const float* wd  = (const float*)d_in[4];
  float* out = (float*)d_out;

  char* ws = (char*)d_ws;
  int*   counts   = (int*)ws;                                       // 256 B
  int*   tok_slot = (int*)(ws + 256);                               // 131072 B
  float* w_slot   = (float*)(ws + 131328);                          // 131072 B
  int*   inv      = (int*)(ws + 262400);                            // 65536 B
  unsigned short* xb   = (unsigned short*)(ws + 327936);            // 8.39 MB
  unsigned short* h_ws = (unsigned short*)(ws + 8716544);           // 50.3 MB
  unsigned short* wguT = (unsigned short*)(ws + 59048192);          // 201.3 MB
  unsigned short* wdT  = (unsigned short*)(ws + 260374784);         // 100.7 MB
  float*          y_ws = (float*)(ws + 361038080);                  // 268.4 MB
  const size_t NEED = 629473536ULL;

  hipMemsetAsync(d_ws, 0, 327936, stream);                          // counts + slots + inv

  cvt_x_kernel<<<dim3((TT * HH) / (256 * 8)), dim3(256), 0, stream>>>(x, xb);
  router_kernel<<<dim3(TT), dim3(256), 0, stream>>>(x, gw, gb, counts, tok_slot, w_slot, inv);

  if (ws_size >= NEED) {
    cvt_w_kernel<<<dim3((2 * ID) / 64, HH / 64, NE), dim3(256), 0, stream>>>(wgu, wguT, HH, 2 * ID);
    cvt_w_kernel<<<dim3(HH / 64, ID / 64, NE), dim3(256), 0, stream>>>(wd, wdT, ID, HH);
    gu4_kernel<<<dim3(ID / 64, CAP / 128, NE), dim3(256), 0, stream>>>(xb, wguT, counts, tok_slot, h_ws);
    down4_kernel<<<dim3(HH / 128, CAP / 128, NE), dim3(256), 0, stream>>>(h_ws, wdT, counts, w_slot, y_ws);
    combine_kernel<<<dim3(TT), dim3(256), 0, stream>>>(y_ws, inv, out);
  } else {
    hipMemsetAsync(d_out, 0, (size_t)out_size * sizeof(float), stream);
    gu_kernel<<<dim3(ID / 64, CAP / 128, NE), dim3(256), 0, stream>>>(xb, wgu, counts, tok_slot, h_ws);
    down_kernel<<<dim3(HH / 128, CAP / 128, NE), dim3(256), 0, stream>>>(h_ws, wd, counts, tok_slot, w_slot, out);
  }
}